// Round 1
// baseline (32.503 us; speedup 1.0000x reference)
//
#include <hip/hip_runtime.h>
#include <math.h>

#define NS 21          // percept rows (index 0 unused, idx in [1,20])
#define NPAIR (NS*NS)  // 441 precomputed pairs

__global__ __launch_bounds__(256) void rank_rt_kernel(
    const int*   __restrict__ idx,      // (nrows, 5)
    const float* __restrict__ percept,  // (21, 3)
    const float* __restrict__ w,        // (3,)
    const float* __restrict__ rho_p,
    const float* __restrict__ beta_p,
    const float* __restrict__ tau_p,
    const float* __restrict__ gamma_p,
    const float* __restrict__ upper_p,
    const float* __restrict__ mid_p,
    const float* __restrict__ rate_p,
    float* __restrict__ out,            // p: nrows*4, then rt: nrows
    int nrows)
{
    __shared__ float s_tab[NPAIR];      // s(q,r)
    __shared__ float sls_tab[NPAIR];    // s*log(s)
    __shared__ float pz[NS * 3];

    const float rho   = rho_p[0];
    const float beta  = beta_p[0];
    const float tau   = tau_p[0];
    const float gamma = gamma_p[0];
    const float upper = upper_p[0];
    const float mid   = mid_p[0];
    const float rate  = rate_p[0];
    const float w0 = w[0], w1 = w[1], w2 = w[2];
    const float inv_rho = 1.0f / rho;

    // Stage percept into LDS
    for (int i = threadIdx.x; i < NS * 3; i += blockDim.x)
        pz[i] = percept[i];
    __syncthreads();

    // Build the 441-entry similarity table (each block redundantly; cheap)
    for (int e = threadIdx.x; e < NPAIR; e += blockDim.x) {
        int q = e / NS;
        int r = e - q * NS;
        float dx = fabsf(pz[q * 3 + 0] - pz[r * 3 + 0]);
        float dy = fabsf(pz[q * 3 + 1] - pz[r * 3 + 1]);
        float dz = fabsf(pz[q * 3 + 2] - pz[r * 3 + 2]);
        float acc = w0 * powf(dx, rho) + w1 * powf(dy, rho) + w2 * powf(dz, rho);
        float d = powf(acc, inv_rho);
        float s = expf(-beta * powf(d, tau)) + gamma;
        s_tab[e]   = s;
        sls_tab[e] = s * logf(s);
    }
    __syncthreads();

    const int stride = gridDim.x * blockDim.x;
    for (int row = blockIdx.x * blockDim.x + threadIdx.x; row < nrows; row += stride) {
        const int base = row * 5;
        int q  = idx[base + 0];
        int r0 = idx[base + 1];
        int r1 = idx[base + 2];
        int r2 = idx[base + 3];
        int r3 = idx[base + 4];
        int qb = q * NS;

        float s0 = s_tab[qb + r0];
        float s1 = s_tab[qb + r1];
        float s2 = s_tab[qb + r2];
        float s3 = s_tab[qb + r3];
        float t0 = sls_tab[qb + r0];
        float t1 = sls_tab[qb + r1];
        float t2 = sls_tab[qb + r2];
        float t3 = sls_tab[qb + r3];

        float S = (s0 + s1) + (s2 + s3);
        float T = (t0 + t1) + (t2 + t3);
        float invS = 1.0f / S;

        // entropy = -sum p log p = log(S) - (1/S) * sum s_j log s_j
        float ent = logf(S) - T * invS;
        float rt  = upper / (1.0f + expf(-rate * (ent - mid)));

        float4 p;
        p.x = s0 * invS;
        p.y = s1 * invS;
        p.z = s2 * invS;
        p.w = s3 * invS;
        *reinterpret_cast<float4*>(out + (size_t)row * 4) = p;
        out[(size_t)nrows * 4 + row] = rt;
    }
}

extern "C" void kernel_launch(void* const* d_in, const int* in_sizes, int n_in,
                              void* d_out, int out_size, void* d_ws, size_t ws_size,
                              hipStream_t stream) {
    const int*   idx     = (const int*)  d_in[0];
    const float* percept = (const float*)d_in[1];
    const float* w       = (const float*)d_in[2];
    const float* rho     = (const float*)d_in[3];
    const float* beta    = (const float*)d_in[4];
    const float* tau     = (const float*)d_in[5];
    const float* gamma   = (const float*)d_in[6];
    const float* upper   = (const float*)d_in[7];
    const float* mid     = (const float*)d_in[8];
    const float* rate    = (const float*)d_in[9];
    float* out = (float*)d_out;

    const int nrows = in_sizes[0] / 5;
    const int block = 256;
    int grid = 2048;  // grid-stride: 4 rows/thread at B=2M

    rank_rt_kernel<<<grid, block, 0, stream>>>(
        idx, percept, w, rho, beta, tau, gamma, upper, mid, rate, out, nrows);
}

// Round 2
// 32.326 us; speedup vs baseline: 1.0055x; 1.0055x over previous
//
#include <hip/hip_runtime.h>
#include <math.h>

#define NS 21          // percept rows (index 0 unused, idx in [1,20])
#define NPAIR (NS*NS)  // 441 precomputed pairs

__global__ __launch_bounds__(256) void rank_rt_kernel(
    const int*   __restrict__ idx,      // (nrows, 5)
    const float* __restrict__ percept,  // (21, 3)
    const float* __restrict__ w,        // (3,)
    const float* __restrict__ rho_p,
    const float* __restrict__ beta_p,
    const float* __restrict__ tau_p,
    const float* __restrict__ gamma_p,
    const float* __restrict__ upper_p,
    const float* __restrict__ mid_p,
    const float* __restrict__ rate_p,
    float* __restrict__ out,            // p: nrows*4, then rt: nrows
    int nrows)
{
    __shared__ float2 tab[NPAIR];       // {s, s*log(s)} per (q,r)
    __shared__ float pz[NS * 3];

    const float rho   = rho_p[0];
    const float beta  = beta_p[0];
    const float tau   = tau_p[0];
    const float gamma = gamma_p[0];
    const float upper = upper_p[0];
    const float mid   = mid_p[0];
    const float rate  = rate_p[0];
    const float w0 = w[0], w1 = w[1], w2 = w[2];
    const float inv_rho = 1.0f / rho;

    for (int i = threadIdx.x; i < NS * 3; i += blockDim.x)
        pz[i] = percept[i];
    __syncthreads();

    // Build the 441-entry {s, s*log s} table (redundant per block; 2 entries/thread)
    for (int e = threadIdx.x; e < NPAIR; e += blockDim.x) {
        int q = e / NS;
        int r = e - q * NS;
        float dx = fabsf(pz[q * 3 + 0] - pz[r * 3 + 0]);
        float dy = fabsf(pz[q * 3 + 1] - pz[r * 3 + 1]);
        float dz = fabsf(pz[q * 3 + 2] - pz[r * 3 + 2]);
        float acc = w0 * powf(dx, rho) + w1 * powf(dy, rho) + w2 * powf(dz, rho);
        float d = powf(acc, inv_rho);
        float s = expf(-beta * powf(d, tau)) + gamma;
        float2 e2; e2.x = s; e2.y = s * logf(s);
        tab[e] = e2;
    }
    __syncthreads();

    const size_t t    = (size_t)blockIdx.x * blockDim.x + threadIdx.x;
    const size_t row0 = t * 4;
    if (row0 >= (size_t)nrows) return;

    if (row0 + 4 <= (size_t)nrows) {
        // 4 rows: 20 ints = 5 x int4 (16B-aligned: row0*20B is a multiple of 80)
        const int4* ip = reinterpret_cast<const int4*>(idx + row0 * 5);
        int4 a0 = ip[0], a1 = ip[1], a2 = ip[2], a3 = ip[3], a4 = ip[4];
        const int v[20] = { a0.x, a0.y, a0.z, a0.w,
                            a1.x, a1.y, a1.z, a1.w,
                            a2.x, a2.y, a2.z, a2.w,
                            a3.x, a3.y, a3.z, a3.w,
                            a4.x, a4.y, a4.z, a4.w };
        float rt_arr[4];
        #pragma unroll
        for (int k = 0; k < 4; ++k) {
            const int qb = v[5 * k] * NS;
            float2 e0 = tab[qb + v[5 * k + 1]];
            float2 e1 = tab[qb + v[5 * k + 2]];
            float2 e2 = tab[qb + v[5 * k + 3]];
            float2 e3 = tab[qb + v[5 * k + 4]];

            float S = (e0.x + e1.x) + (e2.x + e3.x);
            float T = (e0.y + e1.y) + (e2.y + e3.y);
            float invS = 1.0f / S;

            float ent = logf(S) - T * invS;      // -sum p log p
            rt_arr[k] = upper / (1.0f + expf(-rate * (ent - mid)));

            float4 p;
            p.x = e0.x * invS;
            p.y = e1.x * invS;
            p.z = e2.x * invS;
            p.w = e3.x * invS;
            *reinterpret_cast<float4*>(out + (row0 + k) * 4) = p;
        }
        float4 rt4; rt4.x = rt_arr[0]; rt4.y = rt_arr[1]; rt4.z = rt_arr[2]; rt4.w = rt_arr[3];
        *reinterpret_cast<float4*>(out + (size_t)nrows * 4 + row0) = rt4;
    } else {
        // tail (nrows not divisible by 4): scalar path
        for (size_t row = row0; row < (size_t)nrows; ++row) {
            const size_t base = row * 5;
            int qb = idx[base] * NS;
            float2 e0 = tab[qb + idx[base + 1]];
            float2 e1 = tab[qb + idx[base + 2]];
            float2 e2 = tab[qb + idx[base + 3]];
            float2 e3 = tab[qb + idx[base + 4]];
            float S = (e0.x + e1.x) + (e2.x + e3.x);
            float T = (e0.y + e1.y) + (e2.y + e3.y);
            float invS = 1.0f / S;
            float ent = logf(S) - T * invS;
            float rt = upper / (1.0f + expf(-rate * (ent - mid)));
            float4 p;
            p.x = e0.x * invS; p.y = e1.x * invS; p.z = e2.x * invS; p.w = e3.x * invS;
            *reinterpret_cast<float4*>(out + row * 4) = p;
            out[(size_t)nrows * 4 + row] = rt;
        }
    }
}

extern "C" void kernel_launch(void* const* d_in, const int* in_sizes, int n_in,
                              void* d_out, int out_size, void* d_ws, size_t ws_size,
                              hipStream_t stream) {
    const int*   idx     = (const int*)  d_in[0];
    const float* percept = (const float*)d_in[1];
    const float* w       = (const float*)d_in[2];
    const float* rho     = (const float*)d_in[3];
    const float* beta    = (const float*)d_in[4];
    const float* tau     = (const float*)d_in[5];
    const float* gamma   = (const float*)d_in[6];
    const float* upper   = (const float*)d_in[7];
    const float* mid     = (const float*)d_in[8];
    const float* rate    = (const float*)d_in[9];
    float* out = (float*)d_out;

    const int nrows = in_sizes[0] / 5;
    const int block = 256;
    const int quads = (nrows + 3) / 4;          // rows handled 4-per-thread
    const int grid  = (quads + block - 1) / block;

    rank_rt_kernel<<<grid, block, 0, stream>>>(
        idx, percept, w, rho, beta, tau, gamma, upper, mid, rate, out, nrows);
}